// Round 1
// baseline (3663.525 us; speedup 1.0000x reference)
//
#include <hip/hip_runtime.h>
#include <math.h>

#define TOKENS 8192        // b(4) * T(2048)
#define DM 256
#define T_CTX 2048
#define NH 8
#define DK 32
#define DH 1024
#define NDICT 8192

__device__ __forceinline__ float wave_sum(float v) {
#pragma unroll
  for (int off = 32; off > 0; off >>= 1) v += __shfl_xor(v, off, 64);
  return v;
}

// woS[l][v][d] = sum_h wo[l][h][v][d]
__global__ __launch_bounds__(256) void wo_sum_kernel(const float* __restrict__ wo,
                                                     float* __restrict__ woS) {
  int idx = blockIdx.x * 256 + threadIdx.x;  // 4 * 32 * 256 = 32768 total
  int l = idx >> 13;
  int r = idx & 8191;
  float s = 0.f;
#pragma unroll
  for (int hh = 0; hh < 8; ++hh) s += wo[(size_t)(l * 8 + hh) * 8192 + r];
  woS[idx] = s;
}

__global__ __launch_bounds__(256) void embed_ln_kernel(
    const int* __restrict__ x, const float* __restrict__ emb,
    const float* __restrict__ pos, float* __restrict__ h) {
  int tok = blockIdx.x;
  int t = tok & (T_CTX - 1);
  int tid = threadIdx.x;
  int id = x[tok];
  float val = emb[(size_t)id * DM + tid] + pos[(size_t)t * DM + tid];
  __shared__ float red[4];
  int lane = tid & 63, wv = tid >> 6;
  float s = wave_sum(val);
  if (lane == 0) red[wv] = s;
  __syncthreads();
  float mean = (red[0] + red[1] + red[2] + red[3]) * (1.f / 256.f);
  __syncthreads();
  float dv = val - mean;
  float s2 = wave_sum(dv * dv);
  if (lane == 0) red[wv] = s2;
  __syncthreads();
  float var = (red[0] + red[1] + red[2] + red[3]) * (1.f / 256.f);
  h[(size_t)tok * DM + tid] = dv / sqrtf(var + 1e-5f);
}

// 8 tokens per block; thread = (head, j). q/k/v layout: [b*NH+h][t][32]
__global__ __launch_bounds__(256) void qkv_kernel(
    const float* __restrict__ h, const float* __restrict__ wq,
    const float* __restrict__ wk, const float* __restrict__ wv,
    float* __restrict__ q, float* __restrict__ k, float* __restrict__ v) {
  __shared__ float hs[8][DM];
  int tid = threadIdx.x;
  int tok0 = blockIdx.x * 8;
  for (int i = tid; i < 8 * DM; i += 256) hs[i >> 8][i & 255] = h[(size_t)tok0 * DM + i];
  __syncthreads();
  int head = tid >> 5, j = tid & 31;
  const float* Wq = wq + (size_t)head * (DM * DK) + j;
  const float* Wk = wk + (size_t)head * (DM * DK) + j;
  const float* Wv = wv + (size_t)head * (DM * DK) + j;
  float aq[8] = {0, 0, 0, 0, 0, 0, 0, 0};
  float ak[8] = {0, 0, 0, 0, 0, 0, 0, 0};
  float av[8] = {0, 0, 0, 0, 0, 0, 0, 0};
  for (int m = 0; m < DM; ++m) {
    float wqm = Wq[(size_t)m * DK], wkm = Wk[(size_t)m * DK], wvm = Wv[(size_t)m * DK];
#pragma unroll
    for (int tk = 0; tk < 8; ++tk) {
      float hm = hs[tk][m];
      aq[tk] = fmaf(hm, wqm, aq[tk]);
      ak[tk] = fmaf(hm, wkm, ak[tk]);
      av[tk] = fmaf(hm, wvm, av[tk]);
    }
  }
  int b = tok0 >> 11;
  int t = tok0 & (T_CTX - 1);
  int bh = b * NH + head;
  size_t base = ((size_t)bh * T_CTX + t) * DK + j;
#pragma unroll
  for (int tk = 0; tk < 8; ++tk) {
    q[base + (size_t)tk * DK] = aq[tk];
    k[base + (size_t)tk * DK] = ak[tk];
    v[base + (size_t)tk * DK] = av[tk];
  }
}

// block = (bh, t-tile of 64). 256 threads = 64 t-rows x 4 j-parts.
// po[bh][t][32] = per-head normalized attention output.
__global__ __launch_bounds__(256) void attn_kernel(
    const float* __restrict__ q, const float* __restrict__ k,
    const float* __restrict__ v, float* __restrict__ po) {
  __shared__ float Ks[64][DK];
  __shared__ float Vs[64][DK];
  int blk = blockIdx.x;
  int bh = blk >> 5;  // 0..31
  int tt = blk & 31;  // t-tile
  int tid = threadIdx.x;
  int tl = tid >> 2;  // t-row within tile
  int p = tid & 3;    // j-part (8 dims each)
  int t = tt * 64 + tl;
  const float* qrow = q + ((size_t)bh * T_CTX + t) * DK + p * 8;
  float qr[8];
  *(float4*)&qr[0] = *(const float4*)&qrow[0];
  *(float4*)&qr[4] = *(const float4*)&qrow[4];
  const float* kbase = k + (size_t)bh * T_CTX * DK;
  const float* vbase = v + (size_t)bh * T_CTX * DK;
  float acc[8] = {0, 0, 0, 0, 0, 0, 0, 0};
  float den = 0.f;
  int fo = tid * 8;
  float* ksm = &Ks[0][0];
  float* vsm = &Vs[0][0];
  for (int ot = 0; ot <= tt; ++ot) {
    __syncthreads();
    size_t gbase = (size_t)ot * (64 * DK) + fo;
    *(float4*)&ksm[fo] = *(const float4*)&kbase[gbase];
    *(float4*)&ksm[fo + 4] = *(const float4*)&kbase[gbase + 4];
    *(float4*)&vsm[fo] = *(const float4*)&vbase[gbase];
    *(float4*)&vsm[fo + 4] = *(const float4*)&vbase[gbase + 4];
    __syncthreads();
    int olim = t - ot * 64;  // allowed: ol <= olim
    for (int ol = 0; ol < 64; ++ol) {
      float4 k0 = *(const float4*)&Ks[ol][p * 8];
      float4 k1 = *(const float4*)&Ks[ol][p * 8 + 4];
      float s0 = fmaf(qr[1], k0.y, qr[0] * k0.x);
      float s1 = fmaf(qr[3], k0.w, qr[2] * k0.z);
      float s2 = fmaf(qr[5], k1.y, qr[4] * k1.x);
      float s3 = fmaf(qr[7], k1.w, qr[6] * k1.z);
      float s = (s0 + s1) + (s2 + s3);
      s += __shfl_xor(s, 1, 64);
      s += __shfl_xor(s, 2, 64);
      float e = (ol <= olim) ? __expf(fminf(s, 50.f)) : 0.f;
      den += e;
      float4 v0 = *(const float4*)&Vs[ol][p * 8];
      float4 v1 = *(const float4*)&Vs[ol][p * 8 + 4];
      acc[0] = fmaf(e, v0.x, acc[0]);
      acc[1] = fmaf(e, v0.y, acc[1]);
      acc[2] = fmaf(e, v0.z, acc[2]);
      acc[3] = fmaf(e, v0.w, acc[3]);
      acc[4] = fmaf(e, v1.x, acc[4]);
      acc[5] = fmaf(e, v1.y, acc[5]);
      acc[6] = fmaf(e, v1.z, acc[6]);
      acc[7] = fmaf(e, v1.w, acc[7]);
    }
  }
  float inv = 1.0f / (den + 1e-10f);
  float* outp = po + ((size_t)bh * T_CTX + t) * DK + p * 8;
  float4 o0 = {acc[0] * inv, acc[1] * inv, acc[2] * inv, acc[3] * inv};
  float4 o1 = {acc[4] * inv, acc[5] * inv, acc[6] * inv, acc[7] * inv};
  *(float4*)&outp[0] = o0;
  *(float4*)&outp[4] = o1;
}

// head-sum po -> x woS -> + residual -> LN. One token per block.
__global__ __launch_bounds__(256) void attnout_ln_kernel(
    const float* __restrict__ po, const float* __restrict__ woS,
    float* __restrict__ h) {
  __shared__ float sh[256];
  __shared__ float vs[32];
  __shared__ float red[4];
  int tok = blockIdx.x;
  int b = tok >> 11, t = tok & (T_CTX - 1);
  int tid = threadIdx.x;
  int hh = tid >> 5, j = tid & 31;
  sh[tid] = po[(((size_t)b * NH + hh) * T_CTX + t) * DK + j];
  __syncthreads();
  if (tid < 32) {
    float s = 0.f;
#pragma unroll
    for (int u = 0; u < 8; ++u) s += sh[u * 32 + tid];
    vs[tid] = s;
  }
  __syncthreads();
  float o = 0.f;
#pragma unroll
  for (int vv = 0; vv < 32; ++vv) o = fmaf(vs[vv], woS[(size_t)vv * DM + tid], o);
  float val = h[(size_t)tok * DM + tid] + o;
  int lane = tid & 63, wv = tid >> 6;
  float s = wave_sum(val);
  if (lane == 0) red[wv] = s;
  __syncthreads();
  float mean = (red[0] + red[1] + red[2] + red[3]) * (1.f / 256.f);
  __syncthreads();
  float dv = val - mean;
  float s2 = wave_sum(dv * dv);
  if (lane == 0) red[wv] = s2;
  __syncthreads();
  float var = (red[0] + red[1] + red[2] + red[3]) * (1.f / 256.f);
  h[(size_t)tok * DM + tid] = dv / sqrtf(var + 1e-5f);
}

// 8 tokens per block: h(256)->relu(1024)->(256), fused residual+LN.
__global__ __launch_bounds__(256) void mlp_kernel(
    const float* __restrict__ h, const float* __restrict__ w0,
    const float* __restrict__ b0, const float* __restrict__ w1,
    float* __restrict__ hout) {
  __shared__ float hsT[DM][8];      // [m][tk]
  __shared__ float ys[8][DH + 4];   // padded
  __shared__ float red[8][4];
  int tid = threadIdx.x;
  int tok0 = blockIdx.x * 8;
  for (int i = tid; i < 8 * DM; i += 256) {
    int tk = i >> 8, m = i & 255;
    hsT[m][tk] = h[(size_t)tok0 * DM + i];
  }
  __syncthreads();
  int u0 = tid * 4;
  float acc[4][8];
  {
    float4 bb = *(const float4*)&b0[u0];
#pragma unroll
    for (int tk = 0; tk < 8; ++tk) {
      acc[0][tk] = bb.x; acc[1][tk] = bb.y; acc[2][tk] = bb.z; acc[3][tk] = bb.w;
    }
  }
  for (int m = 0; m < DM; ++m) {
    float4 w = *(const float4*)&w0[(size_t)m * DH + u0];
    float4 h0 = *(const float4*)&hsT[m][0];
    float4 h1 = *(const float4*)&hsT[m][4];
    float hm[8] = {h0.x, h0.y, h0.z, h0.w, h1.x, h1.y, h1.z, h1.w};
#pragma unroll
    for (int tk = 0; tk < 8; ++tk) {
      acc[0][tk] = fmaf(w.x, hm[tk], acc[0][tk]);
      acc[1][tk] = fmaf(w.y, hm[tk], acc[1][tk]);
      acc[2][tk] = fmaf(w.z, hm[tk], acc[2][tk]);
      acc[3][tk] = fmaf(w.w, hm[tk], acc[3][tk]);
    }
  }
#pragma unroll
  for (int tk = 0; tk < 8; ++tk) {
    float4 y4 = {fmaxf(acc[0][tk], 0.f), fmaxf(acc[1][tk], 0.f),
                 fmaxf(acc[2][tk], 0.f), fmaxf(acc[3][tk], 0.f)};
    *(float4*)&ys[tk][u0] = y4;
  }
  __syncthreads();
  float o[8] = {0, 0, 0, 0, 0, 0, 0, 0};
  for (int kk4 = 0; kk4 < DH / 4; ++kk4) {
    float wa = w1[(size_t)(kk4 * 4 + 0) * DM + tid];
    float wb = w1[(size_t)(kk4 * 4 + 1) * DM + tid];
    float wc = w1[(size_t)(kk4 * 4 + 2) * DM + tid];
    float wd = w1[(size_t)(kk4 * 4 + 3) * DM + tid];
#pragma unroll
    for (int tk = 0; tk < 8; ++tk) {
      float4 y4 = *(const float4*)&ys[tk][kk4 * 4];
      o[tk] = fmaf(y4.x, wa, o[tk]);
      o[tk] = fmaf(y4.y, wb, o[tk]);
      o[tk] = fmaf(y4.z, wc, o[tk]);
      o[tk] = fmaf(y4.w, wd, o[tk]);
    }
  }
  float val[8], mean[8];
  int lane = tid & 63, wv = tid >> 6;
#pragma unroll
  for (int tk = 0; tk < 8; ++tk) {
    val[tk] = h[((size_t)tok0 + tk) * DM + tid] + o[tk];
    float s = wave_sum(val[tk]);
    if (lane == 0) red[tk][wv] = s;
  }
  __syncthreads();
#pragma unroll
  for (int tk = 0; tk < 8; ++tk)
    mean[tk] = (red[tk][0] + red[tk][1] + red[tk][2] + red[tk][3]) * (1.f / 256.f);
  __syncthreads();
#pragma unroll
  for (int tk = 0; tk < 8; ++tk) {
    float dv = val[tk] - mean[tk];
    float s2 = wave_sum(dv * dv);
    if (lane == 0) red[tk][wv] = s2;
  }
  __syncthreads();
#pragma unroll
  for (int tk = 0; tk < 8; ++tk) {
    float var = (red[tk][0] + red[tk][1] + red[tk][2] + red[tk][3]) * (1.f / 256.f);
    hout[((size_t)tok0 + tk) * DM + tid] = (val[tk] - mean[tk]) / sqrtf(var + 1e-5f);
  }
}

// out[token][d] = h[token] . U[:,d] + bias[d]; 128x128x16 tiled SGEMM
#define BM 128
#define BN 128
#define BKU 16
__global__ __launch_bounds__(256) void unembed_kernel(
    const float* __restrict__ h, const float* __restrict__ U,
    const float* __restrict__ bias, float* __restrict__ out) {
  __shared__ float As[BKU][BM];
  __shared__ float Bs[BKU][BN];
  int tid = threadIdx.x;
  int tx = tid & 15, ty = tid >> 4;
  int row0 = blockIdx.y * BM;
  int col0 = blockIdx.x * BN;
  float acc[8][8];
#pragma unroll
  for (int i = 0; i < 8; ++i)
#pragma unroll
    for (int jj = 0; jj < 8; ++jj) acc[i][jj] = 0.f;
  int ar = tid >> 1;
  int akk = (tid & 1) * 8;
  int bkk = tid >> 4;
  int bc = (tid & 15) * 8;
  for (int k0 = 0; k0 < DM; k0 += BKU) {
    __syncthreads();
    float4 a0 = *(const float4*)&h[(size_t)(row0 + ar) * DM + k0 + akk];
    float4 a1 = *(const float4*)&h[(size_t)(row0 + ar) * DM + k0 + akk + 4];
    As[akk + 0][ar] = a0.x; As[akk + 1][ar] = a0.y;
    As[akk + 2][ar] = a0.z; As[akk + 3][ar] = a0.w;
    As[akk + 4][ar] = a1.x; As[akk + 5][ar] = a1.y;
    As[akk + 6][ar] = a1.z; As[akk + 7][ar] = a1.w;
    float4 b0_ = *(const float4*)&U[(size_t)(k0 + bkk) * NDICT + col0 + bc];
    float4 b1_ = *(const float4*)&U[(size_t)(k0 + bkk) * NDICT + col0 + bc + 4];
    *(float4*)&Bs[bkk][bc] = b0_;
    *(float4*)&Bs[bkk][bc + 4] = b1_;
    __syncthreads();
#pragma unroll
    for (int kk = 0; kk < BKU; ++kk) {
      float a[8], bfr[8];
#pragma unroll
      for (int i = 0; i < 8; ++i) a[i] = As[kk][ty + 16 * i];
#pragma unroll
      for (int jj = 0; jj < 8; ++jj) bfr[jj] = Bs[kk][tx + 16 * jj];
#pragma unroll
      for (int i = 0; i < 8; ++i)
#pragma unroll
        for (int jj = 0; jj < 8; ++jj) acc[i][jj] = fmaf(a[i], bfr[jj], acc[i][jj]);
    }
  }
  float bf[8];
#pragma unroll
  for (int jj = 0; jj < 8; ++jj) bf[jj] = bias[col0 + tx + 16 * jj];
#pragma unroll
  for (int i = 0; i < 8; ++i) {
    int row = row0 + ty + 16 * i;
#pragma unroll
    for (int jj = 0; jj < 8; ++jj) {
      int col = col0 + tx + 16 * jj;
      out[(size_t)row * NDICT + col] = acc[i][jj] + bf[jj];
    }
  }
}

extern "C" void kernel_launch(void* const* d_in, const int* in_sizes, int n_in,
                              void* d_out, int out_size, void* d_ws, size_t ws_size,
                              hipStream_t stream) {
  const int* x = (const int*)d_in[0];
  const float* emb = (const float*)d_in[1];
  const float* pos = (const float*)d_in[2];
  const float* wq = (const float*)d_in[3];
  const float* wk = (const float*)d_in[4];
  const float* wv = (const float*)d_in[5];
  const float* wo = (const float*)d_in[6];
  const float* mlp0 = (const float*)d_in[7];
  const float* mlpb = (const float*)d_in[8];
  const float* mlp1 = (const float*)d_in[9];
  const float* unemb = (const float*)d_in[10];
  const float* bias = (const float*)d_in[11];
  float* out = (float*)d_out;

  float* ws = (float*)d_ws;
  const size_t SZ = (size_t)TOKENS * DM;  // 2,097,152 floats
  float* h_ = ws;
  float* q_ = ws + SZ;
  float* k_ = ws + 2 * SZ;
  float* v_ = ws + 3 * SZ;
  float* po_ = ws + 4 * SZ;
  float* woS = ws + 5 * SZ;  // 32768 floats

  wo_sum_kernel<<<128, 256, 0, stream>>>(wo, woS);
  embed_ln_kernel<<<TOKENS, 256, 0, stream>>>(x, emb, pos, h_);
  for (int l = 0; l < 4; ++l) {
    qkv_kernel<<<TOKENS / 8, 256, 0, stream>>>(
        h_, wq + (size_t)l * NH * DM * DK, wk + (size_t)l * NH * DM * DK,
        wv + (size_t)l * NH * DM * DK, q_, k_, v_);
    attn_kernel<<<1024, 256, 0, stream>>>(q_, k_, v_, po_);
    attnout_ln_kernel<<<TOKENS, 256, 0, stream>>>(po_, woS + (size_t)l * DK * DM, h_);
    mlp_kernel<<<TOKENS / 8, 256, 0, stream>>>(
        h_, mlp0 + (size_t)l * DM * DH, mlpb + (size_t)l * DH,
        mlp1 + (size_t)l * DH * DM, h_);
  }
  dim3 g(NDICT / BN, TOKENS / BM);
  unembed_kernel<<<g, 256, 0, stream>>>(h_, unemb, bias, out);
}

// Round 2
// 2383.330 us; speedup vs baseline: 1.5371x; 1.5371x over previous
//
#include <hip/hip_runtime.h>
#include <math.h>

#define TOKENS 8192        // b(4) * T(2048)
#define DM 256
#define T_CTX 2048
#define NH 8
#define DK 32
#define DH 1024
#define NDICT 8192

__device__ __forceinline__ float wave_sum(float v) {
#pragma unroll
  for (int off = 32; off > 0; off >>= 1) v += __shfl_xor(v, off, 64);
  return v;
}

// woS[l][v][d] = sum_h wo[l][h][v][d]
__global__ __launch_bounds__(256) void wo_sum_kernel(const float* __restrict__ wo,
                                                     float* __restrict__ woS) {
  int idx = blockIdx.x * 256 + threadIdx.x;  // 4 * 32 * 256 = 32768 total
  int l = idx >> 13;
  int r = idx & 8191;
  float s = 0.f;
#pragma unroll
  for (int hh = 0; hh < 8; ++hh) s += wo[(size_t)(l * 8 + hh) * 8192 + r];
  woS[idx] = s;
}

__global__ __launch_bounds__(256) void embed_ln_kernel(
    const int* __restrict__ x, const float* __restrict__ emb,
    const float* __restrict__ pos, float* __restrict__ h) {
  int tok = blockIdx.x;
  int t = tok & (T_CTX - 1);
  int tid = threadIdx.x;
  int id = x[tok];
  float val = emb[(size_t)id * DM + tid] + pos[(size_t)t * DM + tid];
  __shared__ float red[4];
  int lane = tid & 63, wv = tid >> 6;
  float s = wave_sum(val);
  if (lane == 0) red[wv] = s;
  __syncthreads();
  float mean = (red[0] + red[1] + red[2] + red[3]) * (1.f / 256.f);
  __syncthreads();
  float dv = val - mean;
  float s2 = wave_sum(dv * dv);
  if (lane == 0) red[wv] = s2;
  __syncthreads();
  float var = (red[0] + red[1] + red[2] + red[3]) * (1.f / 256.f);
  h[(size_t)tok * DM + tid] = dv / sqrtf(var + 1e-5f);
}

// 8 tokens per block; thread = (head, j). q/k/v layout: [b*NH+h][t][32]
__global__ __launch_bounds__(256) void qkv_kernel(
    const float* __restrict__ h, const float* __restrict__ wq,
    const float* __restrict__ wk, const float* __restrict__ wv,
    float* __restrict__ q, float* __restrict__ k, float* __restrict__ v) {
  __shared__ float hs[8][DM];
  int tid = threadIdx.x;
  int tok0 = blockIdx.x * 8;
  for (int i = tid; i < 8 * DM; i += 256) hs[i >> 8][i & 255] = h[(size_t)tok0 * DM + i];
  __syncthreads();
  int head = tid >> 5, j = tid & 31;
  const float* Wq = wq + (size_t)head * (DM * DK) + j;
  const float* Wk = wk + (size_t)head * (DM * DK) + j;
  const float* Wv = wv + (size_t)head * (DM * DK) + j;
  float aq[8] = {0, 0, 0, 0, 0, 0, 0, 0};
  float ak[8] = {0, 0, 0, 0, 0, 0, 0, 0};
  float av[8] = {0, 0, 0, 0, 0, 0, 0, 0};
  for (int m = 0; m < DM; ++m) {
    float wqm = Wq[(size_t)m * DK], wkm = Wk[(size_t)m * DK], wvm = Wv[(size_t)m * DK];
#pragma unroll
    for (int tk = 0; tk < 8; ++tk) {
      float hm = hs[tk][m];
      aq[tk] = fmaf(hm, wqm, aq[tk]);
      ak[tk] = fmaf(hm, wkm, ak[tk]);
      av[tk] = fmaf(hm, wvm, av[tk]);
    }
  }
  int b = tok0 >> 11;
  int t = tok0 & (T_CTX - 1);
  int bh = b * NH + head;
  size_t base = ((size_t)bh * T_CTX + t) * DK + j;
#pragma unroll
  for (int tk = 0; tk < 8; ++tk) {
    q[base + (size_t)tk * DK] = aq[tk];
    k[base + (size_t)tk * DK] = ak[tk];
    v[base + (size_t)tk * DK] = av[tk];
  }
}

// ---- flash-style attention, register-tiled, no per-element shuffles ----
// LDS swizzled layouts: quad index xor'd with (row>>2) to break bank cycles.
__device__ __forceinline__ int kv_off(int r, int c) {  // row stride 32 dwords
  return (r << 5) + ((((c >> 2) ^ (r >> 2)) & 7) << 2) + (c & 3);
}
__device__ __forceinline__ int p_off(int r, int c) {  // row stride 64 dwords
  return (r << 6) + ((((c >> 2) ^ (r >> 2)) & 15) << 2) + (c & 3);
}

// block = (bh, 64-row t-tile), heavy tiles first. 256 threads.
// Phase A: S(64x64) via 4x4 register outer tiles; exp -> P in LDS.
// Phase B: out(64x32) += P*V via (2 rows x 4 vd) register tiles.
__global__ __launch_bounds__(256) void attn_kernel(
    const float* __restrict__ q, const float* __restrict__ k,
    const float* __restrict__ v, float* __restrict__ po) {
  __shared__ float Qs[64 * 32];
  __shared__ float Ks[64 * 32];
  __shared__ float Vs[64 * 32];
  __shared__ float Ps[64 * 64];
  __shared__ float Ds[64];
  int blk = blockIdx.x;
  int bh = blk & 31;
  int tt = 31 - (blk >> 5);  // heavy tiles dispatched first
  int t0 = tt * 64;
  int tid = threadIdx.x;
  int sr = tid >> 2, sc = (tid & 3) * 8;  // staging: 64 rows x 32 cols
  {
    const float* g = q + ((size_t)bh * T_CTX + t0 + sr) * DK + sc;
    float4 a = *(const float4*)g;
    float4 b = *(const float4*)(g + 4);
    *(float4*)&Qs[kv_off(sr, sc)] = a;
    *(float4*)&Qs[kv_off(sr, sc + 4)] = b;
  }
  int trow = tid >> 4, tcol = tid & 15;  // score layout
  int rp = tid >> 3, u8 = tid & 7;       // PV layout
  float den[4] = {0.f, 0.f, 0.f, 0.f};
  float4 acc0 = {0.f, 0.f, 0.f, 0.f};
  float4 acc1 = {0.f, 0.f, 0.f, 0.f};
  const float* kb = k + (size_t)bh * T_CTX * DK;
  const float* vb = v + (size_t)bh * T_CTX * DK;
  for (int ot = 0; ot <= tt; ++ot) {
    __syncthreads();  // protect Ks/Vs vs previous PV reads
    {
      const float* gk = kb + ((size_t)ot * 64 + sr) * DK + sc;
      const float* gv = vb + ((size_t)ot * 64 + sr) * DK + sc;
      float4 k0 = *(const float4*)gk;
      float4 k1 = *(const float4*)(gk + 4);
      float4 v0 = *(const float4*)gv;
      float4 v1 = *(const float4*)(gv + 4);
      *(float4*)&Ks[kv_off(sr, sc)] = k0;
      *(float4*)&Ks[kv_off(sr, sc + 4)] = k1;
      *(float4*)&Vs[kv_off(sr, sc)] = v0;
      *(float4*)&Vs[kv_off(sr, sc + 4)] = v1;
    }
    __syncthreads();
    // ---- Phase A: scores ----
    float s[4][4];
#pragma unroll
    for (int i = 0; i < 4; ++i)
#pragma unroll
      for (int j = 0; j < 4; ++j) s[i][j] = 0.f;
#pragma unroll
    for (int kk = 0; kk < 32; kk += 4) {
      float4 qv[4], kv4[4];
#pragma unroll
      for (int i = 0; i < 4; ++i) qv[i] = *(const float4*)&Qs[kv_off(trow * 4 + i, kk)];
#pragma unroll
      for (int j = 0; j < 4; ++j) kv4[j] = *(const float4*)&Ks[kv_off(tcol * 4 + j, kk)];
#pragma unroll
      for (int i = 0; i < 4; ++i)
#pragma unroll
        for (int j = 0; j < 4; ++j) {
          s[i][j] = fmaf(qv[i].x, kv4[j].x, s[i][j]);
          s[i][j] = fmaf(qv[i].y, kv4[j].y, s[i][j]);
          s[i][j] = fmaf(qv[i].z, kv4[j].z, s[i][j]);
          s[i][j] = fmaf(qv[i].w, kv4[j].w, s[i][j]);
        }
    }
    if (ot < tt) {  // fully unmasked tile
#pragma unroll
      for (int i = 0; i < 4; ++i) {
        float4 pv;
        float e0 = __expf(fminf(s[i][0], 50.f));
        float e1 = __expf(fminf(s[i][1], 50.f));
        float e2 = __expf(fminf(s[i][2], 50.f));
        float e3 = __expf(fminf(s[i][3], 50.f));
        den[i] += (e0 + e1) + (e2 + e3);
        pv.x = e0; pv.y = e1; pv.z = e2; pv.w = e3;
        *(float4*)&Ps[p_off(trow * 4 + i, tcol * 4)] = pv;
      }
    } else {  // diagonal tile: apply causal mask
#pragma unroll
      for (int i = 0; i < 4; ++i) {
        int rt = trow * 4 + i;  // local row == allowed local col limit
        float4 pv;
        float e[4];
#pragma unroll
        for (int j = 0; j < 4; ++j) {
          int co = tcol * 4 + j;
          float ee = __expf(fminf(s[i][j], 50.f));
          e[j] = (co <= rt) ? ee : 0.f;
        }
        den[i] += (e[0] + e[1]) + (e[2] + e[3]);
        pv.x = e[0]; pv.y = e[1]; pv.z = e[2]; pv.w = e[3];
        *(float4*)&Ps[p_off(trow * 4 + i, tcol * 4)] = pv;
      }
    }
    __syncthreads();
    // ---- Phase B: out += P * V ----
#pragma unroll
    for (int ol = 0; ol < 64; ol += 4) {
      float4 p0 = *(const float4*)&Ps[p_off(rp * 2, ol)];
      float4 p1 = *(const float4*)&Ps[p_off(rp * 2 + 1, ol)];
      float4 w0 = *(const float4*)&Vs[kv_off(ol + 0, u8 * 4)];
      float4 w1 = *(const float4*)&Vs[kv_off(ol + 1, u8 * 4)];
      float4 w2 = *(const float4*)&Vs[kv_off(ol + 2, u8 * 4)];
      float4 w3 = *(const float4*)&Vs[kv_off(ol + 3, u8 * 4)];
      acc0.x = fmaf(p0.x, w0.x, acc0.x); acc0.y = fmaf(p0.x, w0.y, acc0.y);
      acc0.z = fmaf(p0.x, w0.z, acc0.z); acc0.w = fmaf(p0.x, w0.w, acc0.w);
      acc1.x = fmaf(p1.x, w0.x, acc1.x); acc1.y = fmaf(p1.x, w0.y, acc1.y);
      acc1.z = fmaf(p1.x, w0.z, acc1.z); acc1.w = fmaf(p1.x, w0.w, acc1.w);
      acc0.x = fmaf(p0.y, w1.x, acc0.x); acc0.y = fmaf(p0.y, w1.y, acc0.y);
      acc0.z = fmaf(p0.y, w1.z, acc0.z); acc0.w = fmaf(p0.y, w1.w, acc0.w);
      acc1.x = fmaf(p1.y, w1.x, acc1.x); acc1.y = fmaf(p1.y, w1.y, acc1.y);
      acc1.z = fmaf(p1.y, w1.z, acc1.z); acc1.w = fmaf(p1.y, w1.w, acc1.w);
      acc0.x = fmaf(p0.z, w2.x, acc0.x); acc0.y = fmaf(p0.z, w2.y, acc0.y);
      acc0.z = fmaf(p0.z, w2.z, acc0.z); acc0.w = fmaf(p0.z, w2.w, acc0.w);
      acc1.x = fmaf(p1.z, w2.x, acc1.x); acc1.y = fmaf(p1.z, w2.y, acc1.y);
      acc1.z = fmaf(p1.z, w2.z, acc1.z); acc1.w = fmaf(p1.z, w2.w, acc1.w);
      acc0.x = fmaf(p0.w, w3.x, acc0.x); acc0.y = fmaf(p0.w, w3.y, acc0.y);
      acc0.z = fmaf(p0.w, w3.z, acc0.z); acc0.w = fmaf(p0.w, w3.w, acc0.w);
      acc1.x = fmaf(p1.w, w3.x, acc1.x); acc1.y = fmaf(p1.w, w3.y, acc1.y);
      acc1.z = fmaf(p1.w, w3.z, acc1.z); acc1.w = fmaf(p1.w, w3.w, acc1.w);
    }
  }
  // reduce den across the 16 tcol lanes (within-wave)
#pragma unroll
  for (int i = 0; i < 4; ++i) {
    float d = den[i];
    d += __shfl_xor(d, 1, 64);
    d += __shfl_xor(d, 2, 64);
    d += __shfl_xor(d, 4, 64);
    d += __shfl_xor(d, 8, 64);
    if (tcol == 0) Ds[trow * 4 + i] = d;
  }
  __syncthreads();
  float inv0 = 1.0f / (Ds[rp * 2] + 1e-10f);
  float inv1 = 1.0f / (Ds[rp * 2 + 1] + 1e-10f);
  float* o0 = po + ((size_t)bh * T_CTX + t0 + rp * 2) * DK + u8 * 4;
  float4 r0 = {acc0.x * inv0, acc0.y * inv0, acc0.z * inv0, acc0.w * inv0};
  float4 r1 = {acc1.x * inv1, acc1.y * inv1, acc1.z * inv1, acc1.w * inv1};
  *(float4*)o0 = r0;
  *(float4*)(o0 + DK) = r1;
}

// head-sum po -> x woS -> + residual -> LN. One token per block.
__global__ __launch_bounds__(256) void attnout_ln_kernel(
    const float* __restrict__ po, const float* __restrict__ woS,
    float* __restrict__ h) {
  __shared__ float sh[256];
  __shared__ float vs[32];
  __shared__ float red[4];
  int tok = blockIdx.x;
  int b = tok >> 11, t = tok & (T_CTX - 1);
  int tid = threadIdx.x;
  int hh = tid >> 5, j = tid & 31;
  sh[tid] = po[(((size_t)b * NH + hh) * T_CTX + t) * DK + j];
  __syncthreads();
  if (tid < 32) {
    float s = 0.f;
#pragma unroll
    for (int u = 0; u < 8; ++u) s += sh[u * 32 + tid];
    vs[tid] = s;
  }
  __syncthreads();
  float o = 0.f;
#pragma unroll
  for (int vv = 0; vv < 32; ++vv) o = fmaf(vs[vv], woS[(size_t)vv * DM + tid], o);
  float val = h[(size_t)tok * DM + tid] + o;
  int lane = tid & 63, wv = tid >> 6;
  float s = wave_sum(val);
  if (lane == 0) red[wv] = s;
  __syncthreads();
  float mean = (red[0] + red[1] + red[2] + red[3]) * (1.f / 256.f);
  __syncthreads();
  float dv = val - mean;
  float s2 = wave_sum(dv * dv);
  if (lane == 0) red[wv] = s2;
  __syncthreads();
  float var = (red[0] + red[1] + red[2] + red[3]) * (1.f / 256.f);
  h[(size_t)tok * DM + tid] = dv / sqrtf(var + 1e-5f);
}

// 8 tokens per block: h(256)->relu(1024)->(256), fused residual+LN.
__global__ __launch_bounds__(256) void mlp_kernel(
    const float* __restrict__ h, const float* __restrict__ w0,
    const float* __restrict__ b0, const float* __restrict__ w1,
    float* __restrict__ hout) {
  __shared__ float hsT[DM][8];      // [m][tk]
  __shared__ float ys[8][DH + 4];   // padded
  __shared__ float red[8][4];
  int tid = threadIdx.x;
  int tok0 = blockIdx.x * 8;
  for (int i = tid; i < 8 * DM; i += 256) {
    int tk = i >> 8, m = i & 255;
    hsT[m][tk] = h[(size_t)tok0 * DM + i];
  }
  __syncthreads();
  int u0 = tid * 4;
  float acc[4][8];
  {
    float4 bb = *(const float4*)&b0[u0];
#pragma unroll
    for (int tk = 0; tk < 8; ++tk) {
      acc[0][tk] = bb.x; acc[1][tk] = bb.y; acc[2][tk] = bb.z; acc[3][tk] = bb.w;
    }
  }
  for (int m = 0; m < DM; ++m) {
    float4 w = *(const float4*)&w0[(size_t)m * DH + u0];
    float4 h0 = *(const float4*)&hsT[m][0];
    float4 h1 = *(const float4*)&hsT[m][4];
    float hm[8] = {h0.x, h0.y, h0.z, h0.w, h1.x, h1.y, h1.z, h1.w};
#pragma unroll
    for (int tk = 0; tk < 8; ++tk) {
      acc[0][tk] = fmaf(w.x, hm[tk], acc[0][tk]);
      acc[1][tk] = fmaf(w.y, hm[tk], acc[1][tk]);
      acc[2][tk] = fmaf(w.z, hm[tk], acc[2][tk]);
      acc[3][tk] = fmaf(w.w, hm[tk], acc[3][tk]);
    }
  }
#pragma unroll
  for (int tk = 0; tk < 8; ++tk) {
    float4 y4 = {fmaxf(acc[0][tk], 0.f), fmaxf(acc[1][tk], 0.f),
                 fmaxf(acc[2][tk], 0.f), fmaxf(acc[3][tk], 0.f)};
    *(float4*)&ys[tk][u0] = y4;
  }
  __syncthreads();
  float o[8] = {0, 0, 0, 0, 0, 0, 0, 0};
  for (int kk4 = 0; kk4 < DH / 4; ++kk4) {
    float wa = w1[(size_t)(kk4 * 4 + 0) * DM + tid];
    float wb = w1[(size_t)(kk4 * 4 + 1) * DM + tid];
    float wc = w1[(size_t)(kk4 * 4 + 2) * DM + tid];
    float wd = w1[(size_t)(kk4 * 4 + 3) * DM + tid];
#pragma unroll
    for (int tk = 0; tk < 8; ++tk) {
      float4 y4 = *(const float4*)&ys[tk][kk4 * 4];
      o[tk] = fmaf(y4.x, wa, o[tk]);
      o[tk] = fmaf(y4.y, wb, o[tk]);
      o[tk] = fmaf(y4.z, wc, o[tk]);
      o[tk] = fmaf(y4.w, wd, o[tk]);
    }
  }
  float val[8], mean[8];
  int lane = tid & 63, wv = tid >> 6;
#pragma unroll
  for (int tk = 0; tk < 8; ++tk) {
    val[tk] = h[((size_t)tok0 + tk) * DM + tid] + o[tk];
    float s = wave_sum(val[tk]);
    if (lane == 0) red[tk][wv] = s;
  }
  __syncthreads();
#pragma unroll
  for (int tk = 0; tk < 8; ++tk)
    mean[tk] = (red[tk][0] + red[tk][1] + red[tk][2] + red[tk][3]) * (1.f / 256.f);
  __syncthreads();
#pragma unroll
  for (int tk = 0; tk < 8; ++tk) {
    float dv = val[tk] - mean[tk];
    float s2 = wave_sum(dv * dv);
    if (lane == 0) red[tk][wv] = s2;
  }
  __syncthreads();
#pragma unroll
  for (int tk = 0; tk < 8; ++tk) {
    float var = (red[tk][0] + red[tk][1] + red[tk][2] + red[tk][3]) * (1.f / 256.f);
    hout[((size_t)tok0 + tk) * DM + tid] = (val[tk] - mean[tk]) / sqrtf(var + 1e-5f);
  }
}

// out[token][d] = h[token] . U[:,d] + bias[d]; 128x128x16 tiled SGEMM
#define BM 128
#define BN 128
#define BKU 16
__global__ __launch_bounds__(256) void unembed_kernel(
    const float* __restrict__ h, const float* __restrict__ U,
    const float* __restrict__ bias, float* __restrict__ out) {
  __shared__ float As[BKU][BM];
  __shared__ float Bs[BKU][BN];
  int tid = threadIdx.x;
  int tx = tid & 15, ty = tid >> 4;
  int row0 = blockIdx.y * BM;
  int col0 = blockIdx.x * BN;
  float acc[8][8];
#pragma unroll
  for (int i = 0; i < 8; ++i)
#pragma unroll
    for (int jj = 0; jj < 8; ++jj) acc[i][jj] = 0.f;
  int ar = tid >> 1;
  int akk = (tid & 1) * 8;
  int bkk = tid >> 4;
  int bc = (tid & 15) * 8;
  for (int k0 = 0; k0 < DM; k0 += BKU) {
    __syncthreads();
    float4 a0 = *(const float4*)&h[(size_t)(row0 + ar) * DM + k0 + akk];
    float4 a1 = *(const float4*)&h[(size_t)(row0 + ar) * DM + k0 + akk + 4];
    As[akk + 0][ar] = a0.x; As[akk + 1][ar] = a0.y;
    As[akk + 2][ar] = a0.z; As[akk + 3][ar] = a0.w;
    As[akk + 4][ar] = a1.x; As[akk + 5][ar] = a1.y;
    As[akk + 6][ar] = a1.z; As[akk + 7][ar] = a1.w;
    float4 b0_ = *(const float4*)&U[(size_t)(k0 + bkk) * NDICT + col0 + bc];
    float4 b1_ = *(const float4*)&U[(size_t)(k0 + bkk) * NDICT + col0 + bc + 4];
    *(float4*)&Bs[bkk][bc] = b0_;
    *(float4*)&Bs[bkk][bc + 4] = b1_;
    __syncthreads();
#pragma unroll
    for (int kk = 0; kk < BKU; ++kk) {
      float a[8], bfr[8];
#pragma unroll
      for (int i = 0; i < 8; ++i) a[i] = As[kk][ty + 16 * i];
#pragma unroll
      for (int jj = 0; jj < 8; ++jj) bfr[jj] = Bs[kk][tx + 16 * jj];
#pragma unroll
      for (int i = 0; i < 8; ++i)
#pragma unroll
        for (int jj = 0; jj < 8; ++jj) acc[i][jj] = fmaf(a[i], bfr[jj], acc[i][jj]);
    }
  }
  float bf[8];
#pragma unroll
  for (int jj = 0; jj < 8; ++jj) bf[jj] = bias[col0 + tx + 16 * jj];
#pragma unroll
  for (int i = 0; i < 8; ++i) {
    int row = row0 + ty + 16 * i;
#pragma unroll
    for (int jj = 0; jj < 8; ++jj) {
      int col = col0 + tx + 16 * jj;
      out[(size_t)row * NDICT + col] = acc[i][jj] + bf[jj];
    }
  }
}

extern "C" void kernel_launch(void* const* d_in, const int* in_sizes, int n_in,
                              void* d_out, int out_size, void* d_ws, size_t ws_size,
                              hipStream_t stream) {
  const int* x = (const int*)d_in[0];
  const float* emb = (const float*)d_in[1];
  const float* pos = (const float*)d_in[2];
  const float* wq = (const float*)d_in[3];
  const float* wk = (const float*)d_in[4];
  const float* wv = (const float*)d_in[5];
  const float* wo = (const float*)d_in[6];
  const float* mlp0 = (const float*)d_in[7];
  const float* mlpb = (const float*)d_in[8];
  const float* mlp1 = (const float*)d_in[9];
  const float* unemb = (const float*)d_in[10];
  const float* bias = (const float*)d_in[11];
  float* out = (float*)d_out;

  float* ws = (float*)d_ws;
  const size_t SZ = (size_t)TOKENS * DM;  // 2,097,152 floats
  float* h_ = ws;
  float* q_ = ws + SZ;
  float* k_ = ws + 2 * SZ;
  float* v_ = ws + 3 * SZ;
  float* po_ = ws + 4 * SZ;
  float* woS = ws + 5 * SZ;  // 32768 floats

  wo_sum_kernel<<<128, 256, 0, stream>>>(wo, woS);
  embed_ln_kernel<<<TOKENS, 256, 0, stream>>>(x, emb, pos, h_);
  for (int l = 0; l < 4; ++l) {
    qkv_kernel<<<TOKENS / 8, 256, 0, stream>>>(
        h_, wq + (size_t)l * NH * DM * DK, wk + (size_t)l * NH * DM * DK,
        wv + (size_t)l * NH * DM * DK, q_, k_, v_);
    attn_kernel<<<1024, 256, 0, stream>>>(q_, k_, v_, po_);
    attnout_ln_kernel<<<TOKENS, 256, 0, stream>>>(po_, woS + (size_t)l * DK * DM, h_);
    mlp_kernel<<<TOKENS / 8, 256, 0, stream>>>(
        h_, mlp0 + (size_t)l * DM * DH, mlpb + (size_t)l * DH,
        mlp1 + (size_t)l * DH * DM, h_);
  }
  dim3 g(NDICT / BN, TOKENS / BM);
  unembed_kernel<<<g, 256, 0, stream>>>(h_, unemb, bias, out);
}